// Round 1
// baseline (3560.351 us; speedup 1.0000x reference)
//
#include <hip/hip_runtime.h>

#define KNN 19          // k-1 (self excluded)
#define SUBS 4          // threads per face in knn kernel
#define FPB 64          // faces per block in knn kernel (FPB*SUBS = 256 threads)

typedef unsigned long long u64;

// ---------------------------------------------------------------------------
// Kernel 1: centroids (float4, SoA-of-structs) + edge vectors (9 floats/face)
// Replicates: centroid = ((v0+v1)+v2)/3 per coord; edge[j] = v[(j+1)%3] - v[j]
// ---------------------------------------------------------------------------
__global__ __launch_bounds__(256) void k_prep(
    const float* __restrict__ verts, const int* __restrict__ faces,
    float4* __restrict__ cent, float* __restrict__ edges, int F) {
  #pragma clang fp contract(off)
  int f = blockIdx.x * blockDim.x + threadIdx.x;
  if (f >= F) return;
  int i0 = faces[f * 3 + 0];
  int i1 = faces[f * 3 + 1];
  int i2 = faces[f * 3 + 2];
  float v0x = verts[i0 * 3 + 0], v0y = verts[i0 * 3 + 1], v0z = verts[i0 * 3 + 2];
  float v1x = verts[i1 * 3 + 0], v1y = verts[i1 * 3 + 1], v1z = verts[i1 * 3 + 2];
  float v2x = verts[i2 * 3 + 0], v2y = verts[i2 * 3 + 1], v2z = verts[i2 * 3 + 2];

  float cx = ((v0x + v1x) + v2x) / 3.0f;
  float cy = ((v0y + v1y) + v2y) / 3.0f;
  float cz = ((v0z + v1z) + v2z) / 3.0f;
  cent[f] = make_float4(cx, cy, cz, 0.0f);

  float* e = edges + (size_t)f * 9;
  e[0] = v1x - v0x; e[1] = v1y - v0y; e[2] = v1z - v0z;   // edge0 = v1-v0
  e[3] = v2x - v1x; e[4] = v2y - v1y; e[5] = v2z - v1z;   // edge1 = v2-v1
  e[6] = v0x - v2x; e[7] = v0y - v2y; e[8] = v0z - v2z;   // edge2 = v0-v2
}

// ---------------------------------------------------------------------------
// Kernel 2: 19-NN per face. SUBS threads per face, each scans j = sub (mod 4),
// maintains a sorted top-19 list of packed keys (f32bits(d2)<<32 | j) in LDS.
// d2 >= 0 so float-bit order == numeric order; low 32 bits give the stable
// lower-index-first tie-break that lax.top_k uses. After the scan, sub 0
// 4-way-merges the sorted lists and writes the 19 global winners.
// ---------------------------------------------------------------------------
__global__ __launch_bounds__(256) void k_knn(
    const float4* __restrict__ cent, int* __restrict__ nearest, int F) {
  #pragma clang fp contract(off)
  __shared__ u64 s_key[256 * KNN];

  int tid = threadIdx.x;
  int fl  = tid >> 2;       // face-local 0..63
  int sub = tid & 3;        // sub-scanner 0..3
  int f   = blockIdx.x * FPB + fl;

  float4 cme = cent[f];
  u64* lst = s_key + tid * KNN;
  #pragma unroll
  for (int p = 0; p < KNN; ++p) lst[p] = ~0ULL;
  u64 thr = ~0ULL;

  #pragma unroll 4
  for (int j = sub; j < F; j += SUBS) {
    if (j == f) continue;
    float4 cj = cent[j];
    float dx = cme.x - cj.x;
    float dy = cme.y - cj.y;
    float dz = cme.z - cj.z;
    float d2 = (dx * dx + dy * dy) + dz * dz;
    u64 key = ((u64)__float_as_uint(d2) << 32) | (unsigned)j;
    if (key < thr) {
      int p = KNN - 1;
      while (p > 0) {
        u64 kk = lst[p - 1];
        if (kk <= key) break;
        lst[p] = kk;
        --p;
      }
      lst[p] = key;
      thr = lst[KNN - 1];
    }
  }
  __syncthreads();

  if (sub == 0) {
    u64* l0 = s_key + (tid + 0) * KNN;
    u64* l1 = s_key + (tid + 1) * KNN;
    u64* l2 = s_key + (tid + 2) * KNN;
    u64* l3 = s_key + (tid + 3) * KNN;
    int h0 = 0, h1 = 0, h2 = 0, h3 = 0;
    u64 k0 = l0[0], k1 = l1[0], k2 = l2[0], k3 = l3[0];
    int* dst = nearest + (size_t)f * KNN;
    for (int o = 0; o < KNN; ++o) {
      u64 km = k0; int sel = 0;
      if (k1 < km) { km = k1; sel = 1; }
      if (k2 < km) { km = k2; sel = 2; }
      if (k3 < km) { km = k3; sel = 3; }
      dst[o] = (int)(unsigned)km;
      if      (sel == 0) { ++h0; k0 = (h0 < KNN) ? l0[h0] : ~0ULL; }
      else if (sel == 1) { ++h1; k1 = (h1 < KNN) ? l1[h1] : ~0ULL; }
      else if (sel == 2) { ++h2; k2 = (h2 < KNN) ? l2[h2] : ~0ULL; }
      else               { ++h3; k3 = (h3 < KNN) ? l3[h3] : ~0ULL; }
    }
  }
}

// ---------------------------------------------------------------------------
// Kernel 3: crossing count per face + weighted block partial sums.
// Replicates jnp.cross (no FMA) and ((x+y)+z) dot order; t/u via IEEE divide;
// NaN/inf comparisons naturally yield mask=false.
// ---------------------------------------------------------------------------
__global__ __launch_bounds__(256) void k_cross(
    const float* __restrict__ edges, const int* __restrict__ nearest,
    const float* __restrict__ probs, float* __restrict__ partial, int F) {
  #pragma clang fp contract(off)
  int f = blockIdx.x * blockDim.x + threadIdx.x;
  float w = 0.0f;
  if (f < F) {
    float e[3][3];
    #pragma unroll
    for (int a = 0; a < 3; ++a)
      #pragma unroll
      for (int c = 0; c < 3; ++c)
        e[a][c] = edges[(size_t)f * 9 + a * 3 + c];

    int cnt = 0;
    for (int n = 0; n < KNN; ++n) {
      int g = nearest[(size_t)f * KNN + n];
      float nb[3][3];
      #pragma unroll
      for (int b = 0; b < 3; ++b)
        #pragma unroll
        for (int c = 0; c < 3; ++c)
          nb[b][c] = edges[(size_t)g * 9 + b * 3 + c];

      #pragma unroll
      for (int a = 0; a < 3; ++a) {
        #pragma unroll
        for (int b = 0; b < 3; ++b) {
          float c0 = e[a][1] * nb[b][2] - e[a][2] * nb[b][1];
          float c1 = e[a][2] * nb[b][0] - e[a][0] * nb[b][2];
          float c2 = e[a][0] * nb[b][1] - e[a][1] * nb[b][0];
          float den = (c0 * e[a][0] + c1 * e[a][1]) + c2 * e[a][2];
          float tn  = (c0 * nb[b][0] + c1 * nb[b][1]) + c2 * nb[b][2];
          float un  = (c0 * e[b][0]  + c1 * e[b][1])  + c2 * e[b][2];
          float t = tn / den;
          float u = un / den;
          if (t >= 0.0f && t <= 1.0f && u >= 0.0f && u <= 1.0f) ++cnt;
        }
      }
    }
    w = probs[f] * (float)cnt;
  }

  __shared__ float red[256];
  red[threadIdx.x] = w;
  __syncthreads();
  #pragma unroll
  for (int s = 128; s > 0; s >>= 1) {
    if (threadIdx.x < s) red[threadIdx.x] += red[threadIdx.x + s];
    __syncthreads();
  }
  if (threadIdx.x == 0) partial[blockIdx.x] = red[0];
}

// ---------------------------------------------------------------------------
// Kernel 4: deterministic final reduction; /F with F=16384 (power of 2, exact)
// ---------------------------------------------------------------------------
__global__ void k_final(const float* __restrict__ partial, float* __restrict__ out,
                        int nblk, float invF) {
  if (threadIdx.x == 0 && blockIdx.x == 0) {
    float s = 0.0f;
    for (int i = 0; i < nblk; ++i) s += partial[i];
    out[0] = s * invF;
  }
}

extern "C" void kernel_launch(void* const* d_in, const int* in_sizes, int n_in,
                              void* d_out, int out_size, void* d_ws, size_t ws_size,
                              hipStream_t stream) {
  const float* verts = (const float*)d_in[0];
  const int*   faces = (const int*)d_in[1];
  const float* probs = (const float*)d_in[2];
  float* out = (float*)d_out;
  const int F = in_sizes[2];   // 16384 faces (face_probs element count)

  char* ws = (char*)d_ws;
  size_t off = 0;
  float4* cent = (float4*)(ws + off); off += (size_t)F * sizeof(float4);      // 256 KB
  float* edges = (float*)(ws + off);  off += (size_t)F * 9 * sizeof(float);   // 576 KB
  int* nearest = (int*)(ws + off);    off += (size_t)F * KNN * sizeof(int);   // 1.2 MB
  float* partial = (float*)(ws + off);

  int nblk3 = (F + 255) / 256;

  k_prep<<<(F + 255) / 256, 256, 0, stream>>>(verts, faces, cent, edges, F);
  k_knn<<<F / FPB, FPB * SUBS, 0, stream>>>(cent, nearest, F);
  k_cross<<<nblk3, 256, 0, stream>>>(edges, nearest, probs, partial, F);
  k_final<<<1, 64, 0, stream>>>(partial, out, nblk3, 1.0f / (float)F);
}

// Round 2
// 613.263 us; speedup vs baseline: 5.8056x; 5.8056x over previous
//
#include <hip/hip_runtime.h>

typedef unsigned long long u64;
typedef unsigned int u32;

#define KNN 19        // neighbors kept (reference k=20 incl. self, minus self)
#define CHUNKS 8      // candidate-range chunks per face (separate blocks)
#define CAP 32        // collect buffer capacity per face
#define NLISTS (CHUNKS * KNN)   // 152 partial values per face

// Branchless sorted-ascending top-KNN insert:  lst'[p] = min(lst[p], max(lst[p-1], x))
__device__ __forceinline__ void net_insert(float lst[KNN], float x) {
  float prev = x;                      // max(lst[-1], x) with lst[-1] = -inf
  #pragma unroll
  for (int p = 0; p < KNN; ++p) {
    float o = lst[p];
    lst[p] = fminf(o, prev);
    prev = fmaxf(o, x);
  }
}

// ---------------------------------------------------------------------------
// Kernel 1: centroids (float4) + edge vectors (3 x float4, padded for aligned loads)
// ---------------------------------------------------------------------------
__global__ __launch_bounds__(256) void k_prep(
    const float* __restrict__ verts, const int* __restrict__ faces,
    float4* __restrict__ cent, float4* __restrict__ edges, int F) {
  #pragma clang fp contract(off)
  int f = blockIdx.x * 256 + threadIdx.x;
  if (f >= F) return;
  int i0 = faces[f * 3 + 0];
  int i1 = faces[f * 3 + 1];
  int i2 = faces[f * 3 + 2];
  float v0x = verts[i0 * 3 + 0], v0y = verts[i0 * 3 + 1], v0z = verts[i0 * 3 + 2];
  float v1x = verts[i1 * 3 + 0], v1y = verts[i1 * 3 + 1], v1z = verts[i1 * 3 + 2];
  float v2x = verts[i2 * 3 + 0], v2y = verts[i2 * 3 + 1], v2z = verts[i2 * 3 + 2];

  cent[f] = make_float4(((v0x + v1x) + v2x) / 3.0f,
                        ((v0y + v1y) + v2y) / 3.0f,
                        ((v0z + v1z) + v2z) / 3.0f, 0.0f);

  edges[f * 3 + 0] = make_float4(v1x - v0x, v1y - v0y, v1z - v0z, 0.0f);
  edges[f * 3 + 1] = make_float4(v2x - v1x, v2y - v1y, v2z - v1z, 0.0f);
  edges[f * 3 + 2] = make_float4(v0x - v2x, v0y - v2y, v0z - v2z, 0.0f);
}

// ---------------------------------------------------------------------------
// Kernel 2: per-(face, chunk) top-19 distances via register min/max network.
// Block = 64 faces x 4 waves; wave w scans j ≡ w (mod 4) in its chunk, so the
// cent[j] load is wave-uniform (HW broadcast). Lists live in registers.
// Epilogue: wave 0 4-way-merges the 4 wave lists -> part[face][chunk][0..18].
// ---------------------------------------------------------------------------
__global__ __launch_bounds__(256) void k_knn1(
    const float4* __restrict__ cent, float* __restrict__ part, int F) {
  #pragma clang fp contract(off)
  __shared__ float s[256 * KNN];

  int tid  = threadIdx.x;
  int lane = tid & 63;        // face within group
  int wave = tid >> 6;        // sub-scanner 0..3
  int fg   = blockIdx.x / CHUNKS;
  int c    = blockIdx.x % CHUNKS;
  int f    = fg * 64 + lane;
  int npc  = F / CHUNKS;      // candidates per chunk (2048)
  int jbase = c * npc;

  float4 cme = cent[f];
  float lst[KNN];
  #pragma unroll
  for (int p = 0; p < KNN; ++p) lst[p] = __builtin_inff();

  #pragma unroll 4
  for (int j = jbase + wave; j < jbase + npc; j += 4) {
    float4 cj = cent[j];
    float dx = cme.x - cj.x;
    float dy = cme.y - cj.y;
    float dz = cme.z - cj.z;
    float d2 = (dx * dx + dy * dy) + dz * dz;
    d2 = (j == f) ? __builtin_inff() : d2;   // exclude self
    net_insert(lst, d2);
  }

  #pragma unroll
  for (int p = 0; p < KNN; ++p) s[tid * KNN + p] = lst[p];
  __syncthreads();

  if (tid < 64) {
    const float* L0 = s + (tid + 0)   * KNN;
    const float* L1 = s + (tid + 64)  * KNN;
    const float* L2 = s + (tid + 128) * KNN;
    const float* L3 = s + (tid + 192) * KNN;
    int h0 = 0, h1 = 0, h2 = 0, h3 = 0;
    float k0 = L0[0], k1 = L1[0], k2 = L2[0], k3 = L3[0];
    float* dst = part + ((size_t)f * CHUNKS + c) * KNN;
    for (int o = 0; o < KNN; ++o) {
      float km = k0; int sel = 0;
      if (k1 < km) { km = k1; sel = 1; }
      if (k2 < km) { km = k2; sel = 2; }
      if (k3 < km) { km = k3; sel = 3; }
      dst[o] = km;
      if      (sel == 0) { ++h0; k0 = (h0 < KNN) ? L0[h0] : __builtin_inff(); }
      else if (sel == 1) { ++h1; k1 = (h1 < KNN) ? L1[h1] : __builtin_inff(); }
      else if (sel == 2) { ++h2; k2 = (h2 < KNN) ? L2[h2] : __builtin_inff(); }
      else               { ++h3; k3 = (h3 < KNN) ? L3[h3] : __builtin_inff(); }
    }
  }
}

// ---------------------------------------------------------------------------
// Kernel 3: tau[f] = exact 19th-smallest d2 = 19th smallest of the 152 partial
// values (union of chunk top-19s contains the global top-19). Also zeroes cnt.
// ---------------------------------------------------------------------------
__global__ __launch_bounds__(64) void k_tau(
    const float* __restrict__ part, float* __restrict__ tau,
    u32* __restrict__ cnt, int F) {
  __shared__ float s[64 * 153];   // row stride 153 (odd*): kills bank conflicts
  int f0 = blockIdx.x * 64;
  for (int i = threadIdx.x; i < 64 * NLISTS; i += 64) {
    int face = i / NLISTS;
    int idx  = i - face * NLISTS;
    s[face * 153 + idx] = part[(size_t)f0 * NLISTS + i - face * NLISTS + (size_t)face * NLISTS];
  }
  __syncthreads();

  float lst[KNN];
  #pragma unroll
  for (int p = 0; p < KNN; ++p) lst[p] = __builtin_inff();
  const float* row = s + threadIdx.x * 153;
  for (int i = 0; i < NLISTS; ++i) net_insert(lst, row[i]);

  int f = f0 + threadIdx.x;
  tau[f] = lst[KNN - 1];
  cnt[f] = 0u;   // reset collect counter (re-zeroed every launch: deterministic)
}

// ---------------------------------------------------------------------------
// Kernel 4: collect all j with d2 <= tau[f] (j != f). d2 expression is
// bit-identical to k_knn1 (same formula, contract off) so count >= 19 and
// == 19 except on exact value ties at tau.
// ---------------------------------------------------------------------------
__global__ __launch_bounds__(256) void k_collect(
    const float4* __restrict__ cent, const float* __restrict__ tau,
    u32* __restrict__ cnt, u64* __restrict__ buf, int F) {
  #pragma clang fp contract(off)
  int tid  = threadIdx.x;
  int lane = tid & 63;
  int wave = tid >> 6;
  int fg   = blockIdx.x / CHUNKS;
  int c    = blockIdx.x % CHUNKS;
  int f    = fg * 64 + lane;
  int npc  = F / CHUNKS;
  int jbase = c * npc;

  float4 cme = cent[f];
  float tf = tau[f];

  for (int j = jbase + wave; j < jbase + npc; j += 4) {
    float4 cj = cent[j];
    float dx = cme.x - cj.x;
    float dy = cme.y - cj.y;
    float dz = cme.z - cj.z;
    float d2 = (dx * dx + dy * dy) + dz * dz;
    if (j != f && d2 <= tf) {
      u32 pos = atomicAdd(&cnt[f], 1u);
      if (pos < CAP)
        buf[(size_t)f * CAP + pos] = ((u64)__float_as_uint(d2) << 32) | (u32)j;
    }
  }
}

// ---------------------------------------------------------------------------
// Kernel 5: crossing count per face (fused neighbor selection) + block sums.
// ---------------------------------------------------------------------------
__device__ __forceinline__ int face_pair(const float e[3][3],
                                         const float4* __restrict__ edges, int g) {
  #pragma clang fp contract(off)
  float nb[3][3];
  #pragma unroll
  for (int b = 0; b < 3; ++b) {
    float4 t = edges[g * 3 + b];
    nb[b][0] = t.x; nb[b][1] = t.y; nb[b][2] = t.z;
  }
  int cc = 0;
  #pragma unroll
  for (int a = 0; a < 3; ++a) {
    #pragma unroll
    for (int b = 0; b < 3; ++b) {
      float c0 = e[a][1] * nb[b][2] - e[a][2] * nb[b][1];
      float c1 = e[a][2] * nb[b][0] - e[a][0] * nb[b][2];
      float c2 = e[a][0] * nb[b][1] - e[a][1] * nb[b][0];
      float den = (c0 * e[a][0] + c1 * e[a][1]) + c2 * e[a][2];
      float tn  = (c0 * nb[b][0] + c1 * nb[b][1]) + c2 * nb[b][2];
      float un  = (c0 * e[b][0]  + c1 * e[b][1])  + c2 * e[b][2];
      float t = tn / den;
      float u = un / den;
      if (t >= 0.0f && t <= 1.0f && u >= 0.0f && u <= 1.0f) ++cc;
    }
  }
  return cc;
}

__global__ __launch_bounds__(256) void k_cross(
    const float4* __restrict__ edges, const u64* __restrict__ buf,
    const u32* __restrict__ cnt, const float* __restrict__ probs,
    float* __restrict__ partial, int F) {
  #pragma clang fp contract(off)
  int f = blockIdx.x * 256 + threadIdx.x;
  float w = 0.0f;
  if (f < F) {
    float e[3][3];
    #pragma unroll
    for (int a = 0; a < 3; ++a) {
      float4 t = edges[f * 3 + a];
      e[a][0] = t.x; e[a][1] = t.y; e[a][2] = t.z;
    }
    int n = (int)cnt[f];
    if (n > CAP) n = CAP;
    int crossings = 0;
    if (n == KNN) {                      // fast path: membership exact
      for (int i = 0; i < KNN; ++i) {
        int g = (u32)buf[(size_t)f * CAP + i];
        crossings += face_pair(e, edges, g);
      }
    } else {                             // ties at tau: stable (d2, idx) rank filter
      for (int i = 0; i < n; ++i) {
        u64 ki = buf[(size_t)f * CAP + i];
        int rank = 0;
        for (int l = 0; l < n; ++l) rank += (buf[(size_t)f * CAP + l] < ki) ? 1 : 0;
        if (rank < KNN) crossings += face_pair(e, edges, (u32)ki);
      }
    }
    w = probs[f] * (float)crossings;
  }

  __shared__ float red[256];
  red[threadIdx.x] = w;
  __syncthreads();
  #pragma unroll
  for (int s = 128; s > 0; s >>= 1) {
    if (threadIdx.x < s) red[threadIdx.x] += red[threadIdx.x + s];
    __syncthreads();
  }
  if (threadIdx.x == 0) partial[blockIdx.x] = red[0];
}

// ---------------------------------------------------------------------------
// Kernel 6: deterministic final reduction; /F exact (F = 2^14)
// ---------------------------------------------------------------------------
__global__ void k_final(const float* __restrict__ partial, float* __restrict__ out,
                        int nblk, float invF) {
  if (threadIdx.x == 0 && blockIdx.x == 0) {
    float s = 0.0f;
    for (int i = 0; i < nblk; ++i) s += partial[i];
    out[0] = s * invF;
  }
}

extern "C" void kernel_launch(void* const* d_in, const int* in_sizes, int n_in,
                              void* d_out, int out_size, void* d_ws, size_t ws_size,
                              hipStream_t stream) {
  const float* verts = (const float*)d_in[0];
  const int*   faces = (const int*)d_in[1];
  const float* probs = (const float*)d_in[2];
  float* out = (float*)d_out;
  const int F = in_sizes[2];   // 16384

  char* ws = (char*)d_ws;
  size_t off = 0;
  float4* cent  = (float4*)(ws + off); off += (size_t)F * sizeof(float4);       // 256 KB
  float4* edges = (float4*)(ws + off); off += (size_t)F * 3 * sizeof(float4);   // 768 KB
  float*  tau   = (float*)(ws + off);  off += (size_t)F * sizeof(float);        // 64 KB
  u32*    cnt   = (u32*)(ws + off);    off += (size_t)F * sizeof(u32);          // 64 KB
  float*  partial = (float*)(ws + off); off += 4096;
  float*  part  = (float*)(ws + off);                 // F * 152 f32 = 10 MB
  u64*    buf   = (u64*)(ws + off);                   // alias: used after part is dead

  int nblk = (F + 255) / 256;   // 64
  int FG = F / 64;              // 256 face groups

  k_prep   <<<nblk, 256, 0, stream>>>(verts, faces, cent, edges, F);
  k_knn1   <<<FG * CHUNKS, 256, 0, stream>>>(cent, part, F);
  k_tau    <<<FG, 64, 0, stream>>>(part, tau, cnt, F);
  k_collect<<<FG * CHUNKS, 256, 0, stream>>>(cent, tau, cnt, buf, F);
  k_cross  <<<nblk, 256, 0, stream>>>(edges, buf, cnt, probs, partial, F);
  k_final  <<<1, 64, 0, stream>>>(partial, out, nblk, 1.0f / (float)F);
}

// Round 3
// 420.267 us; speedup vs baseline: 8.4716x; 1.4592x over previous
//
#include <hip/hip_runtime.h>

typedef unsigned long long u64;
typedef unsigned int u32;

#define KNN 19        // neighbors used (reference k=20 incl. self, minus self)
#define CHUNKS 8      // candidate-range chunks per face (separate blocks)
#define M 4           // per-scanner register list length
#define CAP 64        // collect buffer capacity per face (expect ~20-30)
#define TAU_K 20      // 20th smallest incl. self == 19th smallest excl. self

// ---------------------------------------------------------------------------
// Kernel 1: centroids (float4) + edge vectors (3 x float4)
// ---------------------------------------------------------------------------
__global__ __launch_bounds__(256) void k_prep(
    const float* __restrict__ verts, const int* __restrict__ faces,
    float4* __restrict__ cent, float4* __restrict__ edges, int F) {
  #pragma clang fp contract(off)
  int f = blockIdx.x * 256 + threadIdx.x;
  if (f >= F) return;
  int i0 = faces[f * 3 + 0];
  int i1 = faces[f * 3 + 1];
  int i2 = faces[f * 3 + 2];
  float v0x = verts[i0 * 3 + 0], v0y = verts[i0 * 3 + 1], v0z = verts[i0 * 3 + 2];
  float v1x = verts[i1 * 3 + 0], v1y = verts[i1 * 3 + 1], v1z = verts[i1 * 3 + 2];
  float v2x = verts[i2 * 3 + 0], v2y = verts[i2 * 3 + 1], v2z = verts[i2 * 3 + 2];

  cent[f] = make_float4(((v0x + v1x) + v2x) / 3.0f,
                        ((v0y + v1y) + v2y) / 3.0f,
                        ((v0z + v1z) + v2z) / 3.0f, 0.0f);

  edges[f * 3 + 0] = make_float4(v1x - v0x, v1y - v0y, v1z - v0z, 0.0f);
  edges[f * 3 + 1] = make_float4(v2x - v1x, v2y - v1y, v2z - v1z, 0.0f);
  edges[f * 3 + 2] = make_float4(v0x - v2x, v0y - v2y, v0z - v2z, 0.0f);
}

// ---------------------------------------------------------------------------
// Kernel 2: per-(face,chunk,wave) top-4 d2 via branchless register network.
// Self is NOT excluded (d2=0 lands in its scanner's top-4; tau pass takes the
// 20th smallest incl. self = 19th excl. self — matches reference's k=20).
// No LDS, no merge: each thread stores its sorted 4 as one float4.
// Block = 64 faces x 4 waves; wave-uniform cent[j] loads.
// ---------------------------------------------------------------------------
__global__ __launch_bounds__(256) void k_knn1(
    const float4* __restrict__ cent, float4* __restrict__ part, int F) {
  #pragma clang fp contract(off)
  int tid  = threadIdx.x;
  int lane = tid & 63;        // face within group
  int wave = tid >> 6;        // scanner 0..3
  int fg   = blockIdx.x / CHUNKS;
  int c    = blockIdx.x % CHUNKS;
  int f    = fg * 64 + lane;
  int npc  = F / CHUNKS;      // 2048
  int jbase = c * npc;

  float4 cme = cent[f];
  float l0 = __builtin_inff(), l1 = __builtin_inff();
  float l2 = __builtin_inff(), l3 = __builtin_inff();

  #pragma unroll 8
  for (int j = jbase + wave; j < jbase + npc; j += 4) {
    float4 cj = cent[j];
    float dx = cme.x - cj.x;
    float dy = cme.y - cj.y;
    float dz = cme.z - cj.z;
    float d2 = (dx * dx + dy * dy) + dz * dz;
    // branchless sorted top-4 insert: l'[p] = min(l[p], max(l[p-1], x))
    float o0 = l0, o1 = l1, o2 = l2, o3 = l3;
    l0 = fminf(o0, d2);
    l1 = fminf(o1, fmaxf(o0, d2));
    l2 = fminf(o2, fmaxf(o1, d2));
    l3 = fminf(o3, fmaxf(o2, d2));
  }

  part[((size_t)f * CHUNKS + c) * 4 + wave] = make_float4(l0, l1, l2, l3);
}

// ---------------------------------------------------------------------------
// Kernel 3: tau'[f] = 20th smallest of the 128 union values (valid upper bound
// of the true 19th-excl-self distance: subset order stat >= full order stat,
// and self's 0 is always present). Also zeroes the collect counters.
// ---------------------------------------------------------------------------
__global__ __launch_bounds__(256) void k_tau(
    const float4* __restrict__ part, float* __restrict__ tau,
    u32* __restrict__ cnt, int F) {
  int f = blockIdx.x * 256 + threadIdx.x;
  if (f >= F) return;
  float lst[TAU_K];
  #pragma unroll
  for (int p = 0; p < TAU_K; ++p) lst[p] = __builtin_inff();

  const float4* row = part + (size_t)f * (CHUNKS * 4);
  for (int i = 0; i < CHUNKS * 4; ++i) {
    float4 v = row[i];
    #pragma unroll
    for (int q = 0; q < 4; ++q) {
      float x = (q == 0) ? v.x : (q == 1) ? v.y : (q == 2) ? v.z : v.w;
      float prev = x;
      #pragma unroll
      for (int p = 0; p < TAU_K; ++p) {
        float o = lst[p];
        lst[p] = fminf(o, prev);
        prev = fmaxf(o, x);
      }
    }
  }
  tau[f] = lst[TAU_K - 1];
  cnt[f] = 0u;
}

// ---------------------------------------------------------------------------
// Kernel 4: collect all j != f with d2 <= tau'[f]. d2 expression bit-identical
// to k_knn1 (same formula, contract off) -> superset of the true top-19.
// ---------------------------------------------------------------------------
__global__ __launch_bounds__(256) void k_collect(
    const float4* __restrict__ cent, const float* __restrict__ tau,
    u32* __restrict__ cnt, u64* __restrict__ buf, int F) {
  #pragma clang fp contract(off)
  int tid  = threadIdx.x;
  int lane = tid & 63;
  int wave = tid >> 6;
  int fg   = blockIdx.x / CHUNKS;
  int c    = blockIdx.x % CHUNKS;
  int f    = fg * 64 + lane;
  int npc  = F / CHUNKS;
  int jbase = c * npc;

  float4 cme = cent[f];
  float tf = tau[f];

  #pragma unroll 4
  for (int j = jbase + wave; j < jbase + npc; j += 4) {
    float4 cj = cent[j];
    float dx = cme.x - cj.x;
    float dy = cme.y - cj.y;
    float dz = cme.z - cj.z;
    float d2 = (dx * dx + dy * dy) + dz * dz;
    if (d2 <= tf && j != f) {
      u32 pos = atomicAdd(&cnt[f], 1u);
      if (pos < CAP)
        buf[(size_t)f * CAP + pos] = ((u64)__float_as_uint(d2) << 32) | (u32)j;
    }
  }
}

// ---------------------------------------------------------------------------
// Kernel 5: crossing count per face. Exact top-19 selection among collected
// via packed (d2bits, idx) rank — identical ordering (incl. stable ties) to
// lax.top_k on -d2 with -inf diag. Then 3x3 segment-pair mask count.
// ---------------------------------------------------------------------------
__device__ __forceinline__ int face_pair(const float e[3][3],
                                         const float4* __restrict__ edges, int g) {
  #pragma clang fp contract(off)
  float nb[3][3];
  #pragma unroll
  for (int b = 0; b < 3; ++b) {
    float4 t = edges[g * 3 + b];
    nb[b][0] = t.x; nb[b][1] = t.y; nb[b][2] = t.z;
  }
  int cc = 0;
  #pragma unroll
  for (int a = 0; a < 3; ++a) {
    #pragma unroll
    for (int b = 0; b < 3; ++b) {
      float c0 = e[a][1] * nb[b][2] - e[a][2] * nb[b][1];
      float c1 = e[a][2] * nb[b][0] - e[a][0] * nb[b][2];
      float c2 = e[a][0] * nb[b][1] - e[a][1] * nb[b][0];
      float den = (c0 * e[a][0] + c1 * e[a][1]) + c2 * e[a][2];
      float tn  = (c0 * nb[b][0] + c1 * nb[b][1]) + c2 * nb[b][2];
      float un  = (c0 * e[b][0]  + c1 * e[b][1])  + c2 * e[b][2];
      float t = tn / den;
      float u = un / den;
      if (t >= 0.0f && t <= 1.0f && u >= 0.0f && u <= 1.0f) ++cc;
    }
  }
  return cc;
}

__global__ __launch_bounds__(256) void k_cross(
    const float4* __restrict__ edges, const u64* __restrict__ buf,
    const u32* __restrict__ cnt, const float* __restrict__ probs,
    float* __restrict__ partial, int F) {
  #pragma clang fp contract(off)
  int f = blockIdx.x * 256 + threadIdx.x;
  float w = 0.0f;
  if (f < F) {
    float e[3][3];
    #pragma unroll
    for (int a = 0; a < 3; ++a) {
      float4 t = edges[f * 3 + a];
      e[a][0] = t.x; e[a][1] = t.y; e[a][2] = t.z;
    }
    int n = (int)cnt[f];
    if (n > CAP) n = CAP;
    const u64* row = buf + (size_t)f * CAP;
    int crossings = 0;
    for (int i = 0; i < n; ++i) {
      u64 ki = row[i];
      int rank = 0;
      for (int l = 0; l < n; ++l) rank += (row[l] < ki) ? 1 : 0;
      if (rank < KNN) crossings += face_pair(e, edges, (u32)ki);
    }
    w = probs[f] * (float)crossings;
  }

  __shared__ float red[256];
  red[threadIdx.x] = w;
  __syncthreads();
  #pragma unroll
  for (int s = 128; s > 0; s >>= 1) {
    if (threadIdx.x < s) red[threadIdx.x] += red[threadIdx.x + s];
    __syncthreads();
  }
  if (threadIdx.x == 0) partial[blockIdx.x] = red[0];
}

// ---------------------------------------------------------------------------
// Kernel 6: deterministic final reduction; /F exact (F = 2^14)
// ---------------------------------------------------------------------------
__global__ void k_final(const float* __restrict__ partial, float* __restrict__ out,
                        int nblk, float invF) {
  if (threadIdx.x == 0 && blockIdx.x == 0) {
    float s = 0.0f;
    for (int i = 0; i < nblk; ++i) s += partial[i];
    out[0] = s * invF;
  }
}

extern "C" void kernel_launch(void* const* d_in, const int* in_sizes, int n_in,
                              void* d_out, int out_size, void* d_ws, size_t ws_size,
                              hipStream_t stream) {
  const float* verts = (const float*)d_in[0];
  const int*   faces = (const int*)d_in[1];
  const float* probs = (const float*)d_in[2];
  float* out = (float*)d_out;
  const int F = in_sizes[2];   // 16384

  char* ws = (char*)d_ws;
  size_t off = 0;
  float4* cent  = (float4*)(ws + off); off += (size_t)F * sizeof(float4);       // 256 KB
  float4* edges = (float4*)(ws + off); off += (size_t)F * 3 * sizeof(float4);   // 768 KB
  float*  tau   = (float*)(ws + off);  off += (size_t)F * sizeof(float);        // 64 KB
  u32*    cnt   = (u32*)(ws + off);    off += (size_t)F * sizeof(u32);          // 64 KB
  float*  partial = (float*)(ws + off); off += 4096;
  float4* part  = (float4*)(ws + off);                // F * 32 float4 = 8 MB
  u64*    buf   = (u64*)(ws + off);                   // F * CAP u64 = 8 MB (aliases part; part dead after k_tau)

  int nblk = (F + 255) / 256;   // 64
  int FG = F / 64;              // 256 face groups

  k_prep   <<<nblk, 256, 0, stream>>>(verts, faces, cent, edges, F);
  k_knn1   <<<FG * CHUNKS, 256, 0, stream>>>(cent, part, F);
  k_tau    <<<nblk, 256, 0, stream>>>(part, tau, cnt, F);
  k_collect<<<FG * CHUNKS, 256, 0, stream>>>(cent, tau, cnt, buf, F);
  k_cross  <<<nblk, 256, 0, stream>>>(edges, buf, cnt, probs, partial, F);
  k_final  <<<1, 64, 0, stream>>>(partial, out, nblk, 1.0f / (float)F);
}

// Round 4
// 294.087 us; speedup vs baseline: 12.1065x; 1.4291x over previous
//
#include <hip/hip_runtime.h>

typedef unsigned long long u64;
typedef unsigned int u32;

#define KNN 19        // neighbors used (reference k=20 incl. self, minus self)
#define CHUNKS 8      // candidate-range chunks per face (separate blocks)
#define TAU_K 20      // 20th smallest incl. self == 19th smallest excl. self
#define LCAP 8        // per-thread LDS hit buffer slots in k_collect

// Branchless sorted-ascending top-19 insert on packed (d2bits<<32|idx) keys.
// l'[p] = min(l[p], max(l[p-1], key)), l[-1] = -inf.
__device__ __forceinline__ void net19_u64(u64 L[KNN], u64 key) {
  u64 prev = key;
  #pragma unroll
  for (int p = 0; p < KNN; ++p) {
    u64 o = L[p];
    L[p] = (prev < o) ? prev : o;
    prev = (key < o) ? o : key;
  }
}

// ---------------------------------------------------------------------------
// Kernel 1: centroids (float4) + edge vectors (3 x float4)
// ---------------------------------------------------------------------------
__global__ __launch_bounds__(256) void k_prep(
    const float* __restrict__ verts, const int* __restrict__ faces,
    float4* __restrict__ cent, float4* __restrict__ edges, int F) {
  #pragma clang fp contract(off)
  int f = blockIdx.x * 256 + threadIdx.x;
  if (f >= F) return;
  int i0 = faces[f * 3 + 0];
  int i1 = faces[f * 3 + 1];
  int i2 = faces[f * 3 + 2];
  float v0x = verts[i0 * 3 + 0], v0y = verts[i0 * 3 + 1], v0z = verts[i0 * 3 + 2];
  float v1x = verts[i1 * 3 + 0], v1y = verts[i1 * 3 + 1], v1z = verts[i1 * 3 + 2];
  float v2x = verts[i2 * 3 + 0], v2y = verts[i2 * 3 + 1], v2z = verts[i2 * 3 + 2];

  cent[f] = make_float4(((v0x + v1x) + v2x) / 3.0f,
                        ((v0y + v1y) + v2y) / 3.0f,
                        ((v0z + v1z) + v2z) / 3.0f, 0.0f);

  edges[f * 3 + 0] = make_float4(v1x - v0x, v1y - v0y, v1z - v0z, 0.0f);
  edges[f * 3 + 1] = make_float4(v2x - v1x, v2y - v1y, v2z - v1z, 0.0f);
  edges[f * 3 + 2] = make_float4(v0x - v2x, v0y - v2y, v0z - v2z, 0.0f);
}

// ---------------------------------------------------------------------------
// Kernel 2: per-(face,chunk,wave) top-3 d2 via branchless register network.
// d2 uses fmaf (fast); the tau pass adds a 2e-6 relative margin to cover the
// fma-vs-contract-off difference (<= ~7e-7 rel, no cancellation in the sum).
// Self is included (d2=0); tau takes 20th incl. self = 19th excl. self.
// ---------------------------------------------------------------------------
__global__ __launch_bounds__(256) void k_knn1(
    const float4* __restrict__ cent, float* __restrict__ part3, int F) {
  int tid  = threadIdx.x;
  int lane = tid & 63;        // face within group
  int wave = tid >> 6;        // scanner 0..3
  int fg   = blockIdx.x / CHUNKS;
  int c    = blockIdx.x % CHUNKS;
  int f    = fg * 64 + lane;
  int npc  = F / CHUNKS;      // 2048
  int jbase = c * npc;

  float4 cme = cent[f];
  float l0 = __builtin_inff(), l1 = __builtin_inff(), l2 = __builtin_inff();

  #pragma unroll 8
  for (int j = jbase + wave; j < jbase + npc; j += 4) {
    float4 cj = cent[j];
    float dx = cme.x - cj.x;
    float dy = cme.y - cj.y;
    float dz = cme.z - cj.z;
    float d2 = fmaf(dz, dz, fmaf(dy, dy, dx * dx));
    float o0 = l0, o1 = l1, o2 = l2;
    l0 = fminf(o0, d2);
    l1 = fminf(o1, fmaxf(o0, d2));
    l2 = fminf(o2, fmaxf(o1, d2));
  }

  size_t base = ((size_t)f * (CHUNKS * 4) + (c * 4 + wave)) * 3;
  part3[base + 0] = l0;
  part3[base + 1] = l1;
  part3[base + 2] = l2;
}

// ---------------------------------------------------------------------------
// Kernel 3: tau'[f] = (20th smallest of the 96 union values) * (1 + 2e-6).
// Any-subset order stat >= full-set order stat => valid upper bound of the
// true 19th-excl-self distance; margin covers fma-vs-exact d2 noise.
// Also zeroes the collect counters.
// ---------------------------------------------------------------------------
__global__ __launch_bounds__(256) void k_tau(
    const float* __restrict__ part3, float* __restrict__ tau,
    u32* __restrict__ cnt, int F) {
  int f = blockIdx.x * 256 + threadIdx.x;
  if (f >= F) return;
  float lst[TAU_K];
  #pragma unroll
  for (int p = 0; p < TAU_K; ++p) lst[p] = __builtin_inff();

  const float4* row = (const float4*)(part3 + (size_t)f * 96);   // 24 float4
  for (int i = 0; i < 24; ++i) {
    float4 v = row[i];
    #pragma unroll
    for (int q = 0; q < 4; ++q) {
      float x = (q == 0) ? v.x : (q == 1) ? v.y : (q == 2) ? v.z : v.w;
      float prev = x;
      #pragma unroll
      for (int p = 0; p < TAU_K; ++p) {
        float o = lst[p];
        lst[p] = fminf(o, prev);
        prev = fmaxf(o, x);
      }
    }
  }
  tau[f] = lst[TAU_K - 1] * (1.0f + 2e-6f);
  cnt[f] = 0u;
}

// ---------------------------------------------------------------------------
// Kernel 4: collect all j != f with exact d2 <= tau'[f].
// Hits go to a private per-thread LDS segment (no in-loop atomic latency);
// one atomicAdd per thread post-loop reserves the global slots. Overflow
// (> LCAP local or > cap global) falls back to in-loop atomics / k_select
// full rescan — correctness never depends on the buffers sufficing.
// ---------------------------------------------------------------------------
__global__ __launch_bounds__(256) void k_collect(
    const float4* __restrict__ cent, const float* __restrict__ tau,
    u32* __restrict__ cnt, u64* __restrict__ buf, int F, int cap) {
  #pragma clang fp contract(off)
  __shared__ u64 s_hits[256 * LCAP];   // 16 KB

  int tid  = threadIdx.x;
  int lane = tid & 63;
  int wave = tid >> 6;
  int fg   = blockIdx.x / CHUNKS;
  int c    = blockIdx.x % CHUNKS;
  int f    = fg * 64 + lane;
  int npc  = F / CHUNKS;
  int jbase = c * npc;

  float4 cme = cent[f];
  float tf = tau[f];
  int n = 0;

  #pragma unroll 8
  for (int j = jbase + wave; j < jbase + npc; j += 4) {
    float4 cj = cent[j];
    float dx = cme.x - cj.x;
    float dy = cme.y - cj.y;
    float dz = cme.z - cj.z;
    float d2 = (dx * dx + dy * dy) + dz * dz;    // bit-identical to reference path
    if (d2 <= tf && j != f) {
      u64 key = ((u64)__float_as_uint(d2) << 32) | (u32)j;
      if (n < LCAP) {
        s_hits[tid * LCAP + n] = key;
        ++n;
      } else {                                   // ~never: direct spill
        u32 pos = atomicAdd(&cnt[f], 1u);
        if (pos < (u32)cap) buf[(size_t)f * cap + pos] = key;
      }
    }
  }

  if (n > 0) {
    u32 base = atomicAdd(&cnt[f], (u32)n);
    for (int i = 0; i < n; ++i) {
      u32 pos = base + (u32)i;
      if (pos < (u32)cap) buf[(size_t)f * cap + pos] = s_hits[tid * LCAP + i];
    }
  }
}

// ---------------------------------------------------------------------------
// Kernel 5: exact top-19 per face via u64 network over the collected set
// (same ordering incl. stable index tie-break as lax.top_k on -d2).
// Fallback: full O(F) rescan if the collected set is unusable (never in
// practice; keeps the algorithm exact unconditionally).
// ---------------------------------------------------------------------------
__global__ __launch_bounds__(256) void k_select(
    const float4* __restrict__ cent, const u64* __restrict__ buf,
    const u32* __restrict__ cnt, int* __restrict__ nearest, int F, int cap) {
  #pragma clang fp contract(off)
  int f = blockIdx.x * 256 + threadIdx.x;
  if (f >= F) return;

  u64 L[KNN];
  #pragma unroll
  for (int p = 0; p < KNN; ++p) L[p] = ~0ULL;

  int n = (int)cnt[f];
  if (n >= KNN && n <= cap) {
    const u64* row = buf + (size_t)f * cap;
    for (int i = 0; i < n; ++i) net19_u64(L, row[i]);
  } else {
    float4 cme = cent[f];
    for (int j = 0; j < F; ++j) {
      if (j == f) continue;
      float4 cj = cent[j];
      float dx = cme.x - cj.x;
      float dy = cme.y - cj.y;
      float dz = cme.z - cj.z;
      float d2 = (dx * dx + dy * dy) + dz * dz;
      net19_u64(L, ((u64)__float_as_uint(d2) << 32) | (u32)j);
    }
  }

  #pragma unroll
  for (int p = 0; p < KNN; ++p) nearest[(size_t)f * KNN + p] = (int)(u32)L[p];
}

// ---------------------------------------------------------------------------
// Kernel 6: one thread per (face, neighbor): 3x3 segment-pair crossing count.
// Integer results -> ccbuf (deterministic, no float atomics).
// ---------------------------------------------------------------------------
__global__ __launch_bounds__(256) void k_cross(
    const float4* __restrict__ edges, const int* __restrict__ nearest,
    int* __restrict__ ccbuf, int total) {
  #pragma clang fp contract(off)
  int idx = blockIdx.x * 256 + threadIdx.x;
  if (idx >= total) return;
  int f = idx / KNN;
  int g = nearest[idx];

  float e[3][3], nb[3][3];
  #pragma unroll
  for (int a = 0; a < 3; ++a) {
    float4 t = edges[f * 3 + a];
    e[a][0] = t.x; e[a][1] = t.y; e[a][2] = t.z;
  }
  #pragma unroll
  for (int b = 0; b < 3; ++b) {
    float4 t = edges[g * 3 + b];
    nb[b][0] = t.x; nb[b][1] = t.y; nb[b][2] = t.z;
  }

  int cc = 0;
  #pragma unroll
  for (int a = 0; a < 3; ++a) {
    #pragma unroll
    for (int b = 0; b < 3; ++b) {
      float c0 = e[a][1] * nb[b][2] - e[a][2] * nb[b][1];
      float c1 = e[a][2] * nb[b][0] - e[a][0] * nb[b][2];
      float c2 = e[a][0] * nb[b][1] - e[a][1] * nb[b][0];
      float den = (c0 * e[a][0] + c1 * e[a][1]) + c2 * e[a][2];
      float tn  = (c0 * nb[b][0] + c1 * nb[b][1]) + c2 * nb[b][2];
      float un  = (c0 * e[b][0]  + c1 * e[b][1])  + c2 * e[b][2];
      float t = tn / den;
      float u = un / den;
      if (t >= 0.0f && t <= 1.0f && u >= 0.0f && u <= 1.0f) ++cc;
    }
  }
  ccbuf[idx] = cc;
}

// ---------------------------------------------------------------------------
// Kernel 7: per-face weighted sum w = probs[f] * sum(ccbuf[f][0..18]),
// block-reduced to partial[blockIdx].
// ---------------------------------------------------------------------------
__global__ __launch_bounds__(256) void k_wsum(
    const int* __restrict__ ccbuf, const float* __restrict__ probs,
    float* __restrict__ partial, int F) {
  int f = blockIdx.x * 256 + threadIdx.x;
  float w = 0.0f;
  if (f < F) {
    int c = 0;
    #pragma unroll
    for (int s = 0; s < KNN; ++s) c += ccbuf[(size_t)f * KNN + s];
    w = probs[f] * (float)c;
  }
  __shared__ float red[256];
  red[threadIdx.x] = w;
  __syncthreads();
  #pragma unroll
  for (int s = 128; s > 0; s >>= 1) {
    if (threadIdx.x < s) red[threadIdx.x] += red[threadIdx.x + s];
    __syncthreads();
  }
  if (threadIdx.x == 0) partial[blockIdx.x] = red[0];
}

// ---------------------------------------------------------------------------
// Kernel 8: deterministic final reduction; /F exact (F = 2^14)
// ---------------------------------------------------------------------------
__global__ void k_final(const float* __restrict__ partial, float* __restrict__ out,
                        int nblk, float invF) {
  if (threadIdx.x == 0 && blockIdx.x == 0) {
    float s = 0.0f;
    for (int i = 0; i < nblk; ++i) s += partial[i];
    out[0] = s * invF;
  }
}

extern "C" void kernel_launch(void* const* d_in, const int* in_sizes, int n_in,
                              void* d_out, int out_size, void* d_ws, size_t ws_size,
                              hipStream_t stream) {
  const float* verts = (const float*)d_in[0];
  const int*   faces = (const int*)d_in[1];
  const float* probs = (const float*)d_in[2];
  float* out = (float*)d_out;
  const int F = in_sizes[2];   // 16384
  const int total = F * KNN;

  char* ws = (char*)d_ws;
  size_t off = 0;
  auto take = [&](size_t bytes) { char* p = ws + off; off += (bytes + 255) & ~(size_t)255; return p; };

  float4* cent    = (float4*)take((size_t)F * sizeof(float4));        // 256 KB
  float4* edges   = (float4*)take((size_t)F * 3 * sizeof(float4));    // 768 KB
  float*  tau     = (float*) take((size_t)F * sizeof(float));         // 64 KB
  u32*    cnt     = (u32*)   take((size_t)F * sizeof(u32));           // 64 KB
  int*    nearest = (int*)   take((size_t)total * sizeof(int));       // 1.2 MB
  float*  partial = (float*) take(256 * sizeof(float));

  // Shared region with disjoint lifetimes:
  //   part3 (k_knn1 -> k_tau) | buf (k_collect -> k_select) | ccbuf (k_cross -> k_wsum)
  char* region = ws + off;
  size_t avail = (ws_size > off) ? (ws_size - off) : 0;
  size_t capz = avail / ((size_t)F * sizeof(u64));
  int cap = capz > 128 ? 128 : (int)capz;          // collect capacity per face
  float* part3 = (float*)region;                   // F * 96 f32 = 6.3 MB
  u64*   buf   = (u64*)region;                     // F * cap * 8 B
  int*   ccbuf = (int*)region;                     // total * 4 B = 1.2 MB

  int nblk = (F + 255) / 256;        // 64
  int FG = F / 64;                   // 256 face groups

  k_prep   <<<nblk, 256, 0, stream>>>(verts, faces, cent, edges, F);
  k_knn1   <<<FG * CHUNKS, 256, 0, stream>>>(cent, part3, F);
  k_tau    <<<nblk, 256, 0, stream>>>(part3, tau, cnt, F);
  k_collect<<<FG * CHUNKS, 256, 0, stream>>>(cent, tau, cnt, buf, F, cap);
  k_select <<<nblk, 256, 0, stream>>>(cent, buf, cnt, nearest, F, cap);
  k_cross  <<<(total + 255) / 256, 256, 0, stream>>>(edges, nearest, ccbuf, total);
  k_wsum   <<<nblk, 256, 0, stream>>>(ccbuf, probs, partial, F);
  k_final  <<<1, 64, 0, stream>>>(partial, out, nblk, 1.0f / (float)F);
}